// Round 9
// baseline (138.660 us; speedup 1.0000x reference)
//
#include <hip/hip_runtime.h>
#include <hip/hip_fp16.h>
#include <math.h>

// FAGCN layer, fixed-capacity bucketed scatter->gather, v6 (bisect round):
//   s1[n] = x[n].w1 ; s2[n] = x[n].w2 + b
//   alpha_e = (1-eps)*tanh(s1[row_e] + s2[col_e])
//   out[c]  = eps*x[c] + sum_{e: col_e==c} alpha_e * x[row_e]
//
// R9 = R5 (last PASSING kernel, 136.5us) + ONE change: node_pre and bucket
// fused into a single kernel with 2:1 interleaved block roles (node/edge
// blocks co-resident -> BW-bound and atomic-bound work overlap). Cursor
// zeroing in a dedicated trivial kernel (not memset). Gather is R5-exact
// (fp32 self-term, 4-wide unroll + scalar remainder). R7/R8's failure
// (absmax 19.19, bit-identical with/without nt hints) is structural in the
// R6 diff; this round isolates the fusion variable.

#define NHID 128
#define NNODES 40000
#define NEDGES 640000
#define CAP 64
#define CSTRIDE 16   // cursor padding: 1 cursor per 64 B line

__global__ __launch_bounds__(256) void zero_cursor_kernel(int* __restrict__ cursor) {
    int gid = blockIdx.x * 256 + threadIdx.x;
    if (gid < NNODES * CSTRIDE) cursor[gid] = 0;   // 2500*256 = 640000 exact
}

__global__ __launch_bounds__(256) void pre_bucket_kernel(
    const float* __restrict__ x,
    const float* __restrict__ att_w,
    const float* __restrict__ att_b,
    const int* __restrict__ ei,
    float* __restrict__ s1,
    float* __restrict__ s2,
    __half* __restrict__ xh,
    int* __restrict__ cursor,
    unsigned short* __restrict__ buck) {
    // 7500 blocks, interleaved roles: per group of 3, blocks {0,1}=node,
    // {2}=edge. 5000 node blocks (8 nodes each), 2500 edge blocks (256 edges).
    int g  = blockIdx.x / 3;
    int r3 = blockIdx.x % 3;
    if (r3 != 2) {
        // ---- node side: s1, s2, fp16 copy of x (R5 node_pre body) ----
        int nb   = g * 2 + r3;            // [0, 5000)
        int lane = threadIdx.x & 63;
        int half = lane >> 5;
        int sub  = lane & 31;
        int node = nb * 8 + (threadIdx.x >> 6) * 2 + half;

        float4 xv = ((const float4*)(x + (size_t)node * NHID))[sub];
        float4 w1 = ((const float4*)att_w)[sub];
        float4 w2 = ((const float4*)(att_w + NHID))[sub];

        __half2 h0; h0.x = __float2half_rn(xv.x); h0.y = __float2half_rn(xv.y);
        __half2 h1; h1.x = __float2half_rn(xv.z); h1.y = __float2half_rn(xv.w);
        uint2 hu;
        hu.x = __builtin_bit_cast(unsigned, h0);
        hu.y = __builtin_bit_cast(unsigned, h1);
        ((uint2*)(xh + (size_t)node * NHID))[sub] = hu;

        float p1 = xv.x * w1.x + xv.y * w1.y + xv.z * w1.z + xv.w * w1.w;
        float p2 = xv.x * w2.x + xv.y * w2.y + xv.z * w2.z + xv.w * w2.w;
#pragma unroll
        for (int off = 16; off > 0; off >>= 1) {  // xor stays within 32-group
            p1 += __shfl_xor(p1, off, 64);
            p2 += __shfl_xor(p2, off, 64);
        }
        if (sub == 0) {
            s1[node] = p1;
            s2[node] = p2 + att_b[0];
        }
    } else {
        // ---- edge side: bucket row ids by destination (R5 bucket body) ----
        int e = g * 256 + threadIdx.x;    // [0, 640000) exact
        int r = ei[e];
        int c = ei[NEDGES + e];
        int pos = atomicAdd(&cursor[c * CSTRIDE], 1);
        if (pos < CAP) {
            buck[(size_t)c * CAP + pos] = (unsigned short)r;
        }
    }
}

__device__ __forceinline__ void acc_edge(float4& acc, float a, uint2 u) {
    __half2 h0 = __builtin_bit_cast(__half2, u.x);
    __half2 h1 = __builtin_bit_cast(__half2, u.y);
    float2 f0 = __half22float2(h0);
    float2 f1 = __half22float2(h1);
    acc.x += a * f0.x; acc.y += a * f0.y;
    acc.z += a * f1.x; acc.w += a * f1.y;
}

__global__ __launch_bounds__(256) void gather_kernel(
    const float* __restrict__ x,
    const __half* __restrict__ xh,
    const float* __restrict__ s1,
    const float* __restrict__ s2,
    const float* __restrict__ eps,
    const int* __restrict__ cursor,
    const unsigned short* __restrict__ buck,
    float* __restrict__ out) {
    // 2 nodes per wave: lanes 0-31 -> nodeA, lanes 32-63 -> nodeB (R5-exact)
    int lane = threadIdx.x & 63;
    int half = lane >> 5;
    int sub  = lane & 31;
    int hbase = lane & 32;
    int node = blockIdx.x * 8 + (threadIdx.x >> 6) * 2 + half;
    if (node >= NNODES) return;

    int cnt = cursor[node * CSTRIDE];
    cnt = (cnt < CAP) ? cnt : CAP;

    float e = eps[0];
    float coef = 1.0f - e;
    float s2n = s2[node];

    const unsigned short* bk = buck + (size_t)node * CAP;
    int   r0_l = (sub      < cnt) ? (int)bk[sub]      : 0;
    int   r1_l = (sub + 32 < cnt) ? (int)bk[sub + 32] : 0;
    float a0_l = (sub      < cnt) ? coef * tanhf(s1[r0_l] + s2n) : 0.0f;
    float a1_l = (sub + 32 < cnt) ? coef * tanhf(s1[r1_l] + s2n) : 0.0f;

    float4 xv = ((const float4*)(x + (size_t)node * NHID))[sub];
    float4 acc;
    acc.x = e * xv.x; acc.y = e * xv.y;
    acc.z = e * xv.z; acc.w = e * xv.w;

    int jmax = (cnt < 32) ? cnt : 32;
    int j = 0;
    for (; j + 4 <= jmax; j += 4) {
        int   q0 = __shfl(r0_l, hbase | (j + 0), 64);
        int   q1 = __shfl(r0_l, hbase | (j + 1), 64);
        int   q2 = __shfl(r0_l, hbase | (j + 2), 64);
        int   q3 = __shfl(r0_l, hbase | (j + 3), 64);
        uint2 u0 = ((const uint2*)(xh + (size_t)q0 * NHID))[sub];
        uint2 u1 = ((const uint2*)(xh + (size_t)q1 * NHID))[sub];
        uint2 u2 = ((const uint2*)(xh + (size_t)q2 * NHID))[sub];
        uint2 u3 = ((const uint2*)(xh + (size_t)q3 * NHID))[sub];
        float b0 = __shfl(a0_l, hbase | (j + 0), 64);
        float b1 = __shfl(a0_l, hbase | (j + 1), 64);
        float b2 = __shfl(a0_l, hbase | (j + 2), 64);
        float b3 = __shfl(a0_l, hbase | (j + 3), 64);
        acc_edge(acc, b0, u0);
        acc_edge(acc, b1, u1);
        acc_edge(acc, b2, u2);
        acc_edge(acc, b3, u3);
    }
    for (; j < jmax; j++) {
        int   q = __shfl(r0_l, hbase | j, 64);
        float b = __shfl(a0_l, hbase | j, 64);
        uint2 u = ((const uint2*)(xh + (size_t)q * NHID))[sub];
        acc_edge(acc, b, u);
    }
    for (int j2 = 32; j2 < cnt; j2++) {     // rare: deg > 32
        int   q = __shfl(r1_l, hbase | (j2 - 32), 64);
        float b = __shfl(a1_l, hbase | (j2 - 32), 64);
        uint2 u = ((const uint2*)(xh + (size_t)q * NHID))[sub];
        acc_edge(acc, b, u);
    }

    ((float4*)(out + (size_t)node * NHID))[sub] = acc;
}

extern "C" void kernel_launch(void* const* d_in, const int* in_sizes, int n_in,
                              void* d_out, int out_size, void* d_ws, size_t ws_size,
                              hipStream_t stream) {
    const float* x     = (const float*)d_in[0];
    const int*   ei    = (const int*)d_in[1];
    const float* att_w = (const float*)d_in[2];
    const float* att_b = (const float*)d_in[3];
    const float* eps   = (const float*)d_in[4];
    float* out = (float*)d_out;

    float*          s1     = (float*)d_ws;                 // NNODES
    float*          s2     = s1 + NNODES;                  // NNODES
    __half*         xh     = (__half*)(s2 + NNODES);       // NNODES*NHID (10.24 MB)
    int*            cursor = (int*)(xh + (size_t)NNODES * NHID); // NNODES*CSTRIDE (2.56 MB)
    unsigned short* buck   = (unsigned short*)(cursor + NNODES * CSTRIDE); // NNODES*CAP (5.12 MB)

    zero_cursor_kernel<<<(NNODES * CSTRIDE) / 256, 256, 0, stream>>>(cursor);
    pre_bucket_kernel<<<7500, 256, 0, stream>>>(
        x, att_w, att_b, ei, s1, s2, xh, cursor, buck);
    gather_kernel<<<NNODES / 8, 256, 0, stream>>>(
        x, xh, s1, s2, eps, cursor, buck, out);
}

// Round 10
// 135.860 us; speedup vs baseline: 1.0206x; 1.0206x over previous
//
#include <hip/hip_runtime.h>
#include <hip/hip_fp16.h>
#include <math.h>

// FAGCN layer, fixed-capacity bucketed scatter->gather, v7:
//   s1[n] = x[n].w1 ; s2[n] = x[n].w2 + b
//   alpha_e = (1-eps)*tanh(s1[row_e] + s2[col_e])
//   out[c]  = eps*x[c] + sum_{e: col_e==c} alpha_e * x[row_e]
//
// R10 = R9 (passing frame: zero-kernel + fused pre/bucket interleaved 2:1)
// + gather reads ONLY fp16 xh (self term from xh, err ~5e-4) with 8-deep
// zero-alpha-padded unrolls (no scalar remainder).
// Bisect conclusion being tested: R7/R8's absmax-19 failure was the
// (void)hipMemsetAsync cursor-zeroing silently not executing (poisoned
// cursor -> negative cnt -> loops skipped -> out ~= eps*x). NEVER use
// memset for the cursors; the zero kernel is proven.

#define NHID 128
#define NNODES 40000
#define NEDGES 640000
#define CAP 64
#define CSTRIDE 16   // cursor padding: 1 cursor per 64 B line

__global__ __launch_bounds__(256) void zero_cursor_kernel(int* __restrict__ cursor) {
    int gid = blockIdx.x * 256 + threadIdx.x;
    if (gid < NNODES * CSTRIDE) cursor[gid] = 0;   // 2500*256 = 640000 exact
}

__global__ __launch_bounds__(256) void pre_bucket_kernel(
    const float* __restrict__ x,
    const float* __restrict__ att_w,
    const float* __restrict__ att_b,
    const int* __restrict__ ei,
    float* __restrict__ s1,
    float* __restrict__ s2,
    __half* __restrict__ xh,
    int* __restrict__ cursor,
    unsigned short* __restrict__ buck) {
    // 7500 blocks, interleaved roles: per group of 3, blocks {0,1}=node,
    // {2}=edge. 5000 node blocks (8 nodes each), 2500 edge blocks (256 edges).
    int g  = blockIdx.x / 3;
    int r3 = blockIdx.x % 3;
    if (r3 != 2) {
        // ---- node side: s1, s2, fp16 copy of x ----
        int nb   = g * 2 + r3;            // [0, 5000)
        int lane = threadIdx.x & 63;
        int half = lane >> 5;
        int sub  = lane & 31;
        int node = nb * 8 + (threadIdx.x >> 6) * 2 + half;

        float4 xv = ((const float4*)(x + (size_t)node * NHID))[sub];
        float4 w1 = ((const float4*)att_w)[sub];
        float4 w2 = ((const float4*)(att_w + NHID))[sub];

        __half2 h0; h0.x = __float2half_rn(xv.x); h0.y = __float2half_rn(xv.y);
        __half2 h1; h1.x = __float2half_rn(xv.z); h1.y = __float2half_rn(xv.w);
        uint2 hu;
        hu.x = __builtin_bit_cast(unsigned, h0);
        hu.y = __builtin_bit_cast(unsigned, h1);
        ((uint2*)(xh + (size_t)node * NHID))[sub] = hu;

        float p1 = xv.x * w1.x + xv.y * w1.y + xv.z * w1.z + xv.w * w1.w;
        float p2 = xv.x * w2.x + xv.y * w2.y + xv.z * w2.z + xv.w * w2.w;
#pragma unroll
        for (int off = 16; off > 0; off >>= 1) {  // xor stays within 32-group
            p1 += __shfl_xor(p1, off, 64);
            p2 += __shfl_xor(p2, off, 64);
        }
        if (sub == 0) {
            s1[node] = p1;
            s2[node] = p2 + att_b[0];
        }
    } else {
        // ---- edge side: bucket row ids by destination ----
        int e = g * 256 + threadIdx.x;    // [0, 640000) exact
        int r = ei[e];
        int c = ei[NEDGES + e];
        int pos = atomicAdd(&cursor[c * CSTRIDE], 1);
        if (pos < CAP) {
            buck[(size_t)c * CAP + pos] = (unsigned short)r;
        }
    }
}

__device__ __forceinline__ void acc_edge(float4& acc, float a, uint2 u) {
    __half2 h0 = __builtin_bit_cast(__half2, u.x);
    __half2 h1 = __builtin_bit_cast(__half2, u.y);
    float2 f0 = __half22float2(h0);
    float2 f1 = __half22float2(h1);
    acc.x += a * f0.x; acc.y += a * f0.y;
    acc.z += a * f1.x; acc.w += a * f1.y;
}

__global__ __launch_bounds__(256) void gather_kernel(
    const __half* __restrict__ xh,
    const float* __restrict__ s1,
    const float* __restrict__ s2,
    const float* __restrict__ eps,
    const int* __restrict__ cursor,
    const unsigned short* __restrict__ buck,
    float* __restrict__ out) {
    // 2 nodes per wave: lanes 0-31 -> nodeA, lanes 32-63 -> nodeB
    int lane = threadIdx.x & 63;
    int half = lane >> 5;
    int sub  = lane & 31;
    int hbase = lane & 32;
    int node = blockIdx.x * 8 + (threadIdx.x >> 6) * 2 + half;
    if (node >= NNODES) return;

    int cnt = cursor[node * CSTRIDE];
    cnt = (cnt < CAP) ? cnt : CAP;

    float e = eps[0];
    float coef = 1.0f - e;
    float s2n = s2[node];

    // metadata register-resident: lane sub holds entries sub and sub+32;
    // lanes >= cnt carry alpha=0 so padded iterations contribute nothing
    const unsigned short* bk = buck + (size_t)node * CAP;
    int   r0_l = (sub      < cnt) ? (int)bk[sub]      : 0;
    int   r1_l = (sub + 32 < cnt) ? (int)bk[sub + 32] : 0;
    float a0_l = (sub      < cnt) ? coef * tanhf(s1[r0_l] + s2n) : 0.0f;
    float a1_l = (sub + 32 < cnt) ? coef * tanhf(s1[r1_l] + s2n) : 0.0f;

    const uint2* xrow = (const uint2*)xh;  // row r = uint2 elements [r*32, r*32+32)

    // self term eps*x from fp16 copy (err ~5e-4 on eps*x)
    uint2 selfu = xrow[(size_t)node * 32 + sub];
    float4 acc;
    {
        float2 f0 = __half22float2(__builtin_bit_cast(__half2, selfu.x));
        float2 f1 = __half22float2(__builtin_bit_cast(__half2, selfu.y));
        acc.x = e * f0.x; acc.y = e * f0.y;
        acc.z = e * f1.x; acc.w = e * f1.y;
    }

    // first 32 entries: 8-deep zero-padded unroll (pad rows hit row 0, cached)
    int jmax8 = (((cnt < 32) ? cnt : 32) + 7) & ~7;
    for (int j = 0; j < jmax8; j += 8) {
        int   q[8];
        float bb[8];
        uint2 u[8];
#pragma unroll
        for (int t = 0; t < 8; t++) {
            q[t]  = __shfl(r0_l, hbase | (j + t), 64);
            bb[t] = __shfl(a0_l, hbase | (j + t), 64);
        }
#pragma unroll
        for (int t = 0; t < 8; t++)
            u[t] = xrow[(size_t)q[t] * 32 + sub];
#pragma unroll
        for (int t = 0; t < 8; t++)
            acc_edge(acc, bb[t], u[t]);
    }
    // entries 32..cnt (rare: deg > 32): 4-deep zero-padded
    if (cnt > 32) {
        int j2max4 = ((cnt - 32) + 3) & ~3;
        for (int j = 0; j < j2max4; j += 4) {
            int   q[4];
            float bb[4];
            uint2 u[4];
#pragma unroll
            for (int t = 0; t < 4; t++) {
                q[t]  = __shfl(r1_l, hbase | (j + t), 64);
                bb[t] = __shfl(a1_l, hbase | (j + t), 64);
            }
#pragma unroll
            for (int t = 0; t < 4; t++)
                u[t] = xrow[(size_t)q[t] * 32 + sub];
#pragma unroll
            for (int t = 0; t < 4; t++)
                acc_edge(acc, bb[t], u[t]);
        }
    }

    ((float4*)(out + (size_t)node * NHID))[sub] = acc;
}

extern "C" void kernel_launch(void* const* d_in, const int* in_sizes, int n_in,
                              void* d_out, int out_size, void* d_ws, size_t ws_size,
                              hipStream_t stream) {
    const float* x     = (const float*)d_in[0];
    const int*   ei    = (const int*)d_in[1];
    const float* att_w = (const float*)d_in[2];
    const float* att_b = (const float*)d_in[3];
    const float* eps   = (const float*)d_in[4];
    float* out = (float*)d_out;

    float*          s1     = (float*)d_ws;                 // NNODES
    float*          s2     = s1 + NNODES;                  // NNODES
    __half*         xh     = (__half*)(s2 + NNODES);       // NNODES*NHID (10.24 MB)
    int*            cursor = (int*)(xh + (size_t)NNODES * NHID); // NNODES*CSTRIDE (2.56 MB)
    unsigned short* buck   = (unsigned short*)(cursor + NNODES * CSTRIDE); // NNODES*CAP (5.12 MB)

    zero_cursor_kernel<<<(NNODES * CSTRIDE) / 256, 256, 0, stream>>>(cursor);
    pre_bucket_kernel<<<7500, 256, 0, stream>>>(
        x, att_w, att_b, ei, s1, s2, xh, cursor, buck);
    gather_kernel<<<NNODES / 8, 256, 0, stream>>>(
        xh, s1, s2, eps, cursor, buck, out);
}